// Round 1
// baseline (503.662 us; speedup 1.0000x reference)
//
#include <hip/hip_runtime.h>
#include <hip/hip_bf16.h>

#define NN 8192
#define NE 262144
#define EPSF 1e-9f

typedef __attribute__((ext_vector_type(8))) short short8;
typedef __attribute__((ext_vector_type(4))) float floatx4;

// h0[n][:] = emb[x[n]][:]   (float4-vectorized, 32 float4 per row)
__global__ __launch_bounds__(256) void embed_kernel(const int* __restrict__ x,
    const float* __restrict__ emb, float* __restrict__ h0) {
  int tid = blockIdx.x * 256 + threadIdx.x;   // NN*32 threads
  int n = tid >> 5, j = tid & 31;
  int xi = x[n];
  ((float4*)h0)[(size_t)n * 32 + j] = ((const float4*)emb)[xi * 32 + j];
}

// per edge: ee = edge_attr[e] @ E1w + E1b ; m = relu(h0[src]+ee); agg1[dst] += m
// one wave per edge, lane covers cols {lane, lane+64}
__global__ __launch_bounds__(256) void edge1_kernel(const int* __restrict__ ei,
    const float* __restrict__ ea, const float* __restrict__ W,
    const float* __restrict__ b, const float* __restrict__ h0,
    float* __restrict__ agg) {
  __shared__ float sW[16 * 128];
  __shared__ float sb[128];
  for (int i = threadIdx.x; i < 16 * 128; i += 256) sW[i] = W[i];
  if (threadIdx.x < 128) sb[threadIdx.x] = b[threadIdx.x];
  __syncthreads();
  int lane = threadIdx.x & 63;
  int gw = blockIdx.x * 4 + (threadIdx.x >> 6);  // 8192 waves
  for (int e = gw; e < NE; e += 8192) {
    int s = ei[e], d = ei[NE + e];
    float a0 = sb[lane], a1 = sb[lane + 64];
#pragma unroll
    for (int k = 0; k < 16; ++k) {
      float av = ea[e * 16 + k];
      a0 += av * sW[k * 128 + lane];
      a1 += av * sW[k * 128 + lane + 64];
    }
    float m0 = h0[s * 128 + lane] + a0;
    float m1 = h0[s * 128 + lane + 64] + a1;
    m0 = m0 > 0.f ? m0 : 0.f;
    m1 = m1 > 0.f ? m1 : 0.f;
    unsafeAtomicAdd(&agg[d * 128 + lane], m0);
    unsafeAtomicAdd(&agg[d * 128 + lane + 64], m1);
  }
}

// h1 = leaky_relu(((1+eps)*h0 + agg1) @ W1 + b1)   wave per node, lane = out col (64)
__global__ __launch_bounds__(256) void node1_kernel(const float* __restrict__ h0,
    const float* __restrict__ agg, const float* __restrict__ W,
    const float* __restrict__ b, float* __restrict__ h1) {
  __shared__ float sW[128 * 64];
  __shared__ float st[4][128];
  for (int i = threadIdx.x; i < 128 * 64; i += 256) sW[i] = W[i];
  int lane = threadIdx.x & 63;
  int w = threadIdx.x >> 6;
  __syncthreads();
  for (int it = 0; it < 4; ++it) {
    int n = blockIdx.x * 16 + it * 4 + w;   // 512 blocks * 16 = 8192
    st[w][lane] = (1.0f + EPSF) * h0[n * 128 + lane] + agg[n * 128 + lane];
    st[w][lane + 64] = (1.0f + EPSF) * h0[n * 128 + lane + 64] + agg[n * 128 + lane + 64];
    __syncthreads();
    float acc = b[lane];
#pragma unroll 16
    for (int k = 0; k < 128; ++k) acc += st[w][k] * sW[k * 64 + lane];
    h1[n * 64 + lane] = acc > 0.f ? acc : 0.01f * acc;
    __syncthreads();
  }
}

// per edge: ee = edge_attr[e] @ E2w + E2b ; m = relu(h1[src]+ee); agg2[dst] += m
__global__ __launch_bounds__(256) void edge2_kernel(const int* __restrict__ ei,
    const float* __restrict__ ea, const float* __restrict__ W,
    const float* __restrict__ b, const float* __restrict__ h1,
    float* __restrict__ agg) {
  __shared__ float sW[16 * 64];
  __shared__ float sb[64];
  for (int i = threadIdx.x; i < 16 * 64; i += 256) sW[i] = W[i];
  if (threadIdx.x < 64) sb[threadIdx.x] = b[threadIdx.x];
  __syncthreads();
  int lane = threadIdx.x & 63;
  int gw = blockIdx.x * 4 + (threadIdx.x >> 6);
  for (int e = gw; e < NE; e += 8192) {
    int s = ei[e], d = ei[NE + e];
    float a0 = sb[lane];
#pragma unroll
    for (int k = 0; k < 16; ++k) a0 += ea[e * 16 + k] * sW[k * 64 + lane];
    float m = h1[s * 64 + lane] + a0;
    m = m > 0.f ? m : 0.f;
    unsafeAtomicAdd(&agg[d * 64 + lane], m);
  }
}

// h2 = ((1+eps)*h1 + agg2) @ W2 + b2, stored as bf16 bits (RNE). wave per node.
__global__ __launch_bounds__(256) void node2_kernel(const float* __restrict__ h1,
    const float* __restrict__ agg, const float* __restrict__ W,
    const float* __restrict__ b, short* __restrict__ h2) {
  __shared__ float sW[64 * 32];
  __shared__ float st[4][64];
  for (int i = threadIdx.x; i < 64 * 32; i += 256) sW[i] = W[i];
  int lane = threadIdx.x & 63;
  int w = threadIdx.x >> 6;
  __syncthreads();
  for (int it = 0; it < 4; ++it) {
    int n = blockIdx.x * 16 + it * 4 + w;
    st[w][lane] = (1.0f + EPSF) * h1[n * 64 + lane] + agg[n * 64 + lane];
    __syncthreads();
    int col = lane & 31;
    float acc = b[col];
#pragma unroll 16
    for (int k = 0; k < 64; ++k) acc += st[w][k] * sW[k * 32 + col];
    if (lane < 32) {
      unsigned u = __builtin_bit_cast(unsigned, acc);
      u += 0x7fffu + ((u >> 16) & 1u);          // round-to-nearest-even
      h2[n * 32 + col] = (short)(u >> 16);
    }
    __syncthreads();
  }
}

// out = H2 @ H2^T, H2: 8192x32 bf16. One wave -> 16 rows x 64 cols (4 MFMA tiles).
// A frag: A[m=lane&15][k=(lane>>4)*8 + j]; B frag: B[k][n=lane&15] (same load pattern
// from H2 since B = H2^T). C/D: col=lane&15, row=(lane>>4)*4+reg.
__global__ __launch_bounds__(256) void gemm_kernel(const short* __restrict__ h2,
    float* __restrict__ out) {
  int wid = (blockIdx.x * 256 + threadIdx.x) >> 6;  // 65536 waves
  int lane = threadIdx.x & 63;
  int cg = wid & 127;    // col group of 64
  int rt = wid >> 7;     // row tile of 16
  int r = lane & 15, q = lane >> 4;
  short8 afrag = *(const short8*)(h2 + ((rt * 16 + r) * 32 + q * 8));
  floatx4 acc[4];
#pragma unroll
  for (int t = 0; t < 4; ++t) {
    short8 bfrag = *(const short8*)(h2 + ((cg * 64 + t * 16 + r) * 32 + q * 8));
    floatx4 z = {0.f, 0.f, 0.f, 0.f};
    acc[t] = __builtin_amdgcn_mfma_f32_16x16x32_bf16(afrag, bfrag, z, 0, 0, 0);
  }
  int row_base = rt * 16 + q * 4;
  int col_base = cg * 64 + r;
#pragma unroll
  for (int t = 0; t < 4; ++t)
#pragma unroll
    for (int reg = 0; reg < 4; ++reg)
      out[(size_t)(row_base + reg) * NN + col_base + t * 16] = acc[t][reg];
}

extern "C" void kernel_launch(void* const* d_in, const int* in_sizes, int n_in,
                              void* d_out, int out_size, void* d_ws, size_t ws_size,
                              hipStream_t stream) {
  const int*   x   = (const int*)d_in[0];
  const int*   ei  = (const int*)d_in[1];
  const float* ea  = (const float*)d_in[2];
  const float* emb = (const float*)d_in[3];
  const float* W1  = (const float*)d_in[4];
  const float* b1  = (const float*)d_in[5];
  const float* E1w = (const float*)d_in[6];
  const float* E1b = (const float*)d_in[7];
  const float* W2  = (const float*)d_in[8];
  const float* b2  = (const float*)d_in[9];
  const float* E2w = (const float*)d_in[10];
  const float* E2b = (const float*)d_in[11];

  float* ws   = (float*)d_ws;
  float* h0   = ws;                       // 8192*128 = 1048576 f
  float* h1   = ws + 1048576;             // 8192*64  = 524288 f
  short* h2   = (short*)(ws + 1572864);   // 8192*32 bf16 = 131072 f slots
  float* agg1 = ws + 1703936;             // 1048576 f
  float* agg2 = ws + 2752512;             // 524288 f  -> total ~12.6 MB

  hipMemsetAsync(agg1, 0, (1048576 + 524288) * sizeof(float), stream);
  embed_kernel<<<1024, 256, 0, stream>>>(x, emb, h0);
  edge1_kernel<<<2048, 256, 0, stream>>>(ei, ea, E1w, E1b, h0, agg1);
  node1_kernel<<<512, 256, 0, stream>>>(h0, agg1, W1, b1, h1);
  edge2_kernel<<<2048, 256, 0, stream>>>(ei, ea, E2w, E2b, h1, agg2);
  node2_kernel<<<512, 256, 0, stream>>>(h1, agg2, W2, b2, h2);
  gemm_kernel<<<16384, 256, 0, stream>>>(h2, (float*)d_out);
}